// Round 6
// baseline (414.453 us; speedup 1.0000x reference)
//
#include <hip/hip_runtime.h>

// GraphSAGE 3-layer forward. R14 = R13 with NBLKS 256 -> 64.
//   Rationale: pscatter writes pb in per-(block,bucket) runs of EPB/NB
//   entries. At NBLKS=256 runs were 8 entries = 32B -> every 64B line
//   shared across blocks/XCDs -> ~33MB write amplification (WRITE_SIZE
//   90MB vs 57MB payload). NBLKS=64 -> 32-entry (128B) runs, ~4x less
//   line sharing. Also shrinks histG (200KB) and scan (50048 entries).
//   Everything else frozen at R13 (best-known per stage):
//   agg128/agg64 R8 form (61.4us, VGPR 24), pscatter+gemm0 fused 512thr
//   with LDS-staged weights, LDS-staged standalone GEMMs.
// Per layer: [A | Bt] = H @ [Ws|Wn] (bf16 MFMA, fused self+neigh GEMM)
//            Hnext = relu(A + mean_{e:dst=d} Bt[src[e]]) stored bf16
//            (layer2: A fp32 straight to d_out, no relu)

#define NN 100000
#define NE 1600000
#define BSH 7               // 128 dst-nodes per bucket
#define BND 128
#define NB  782             // ceil(100000/128)
#define NBLKS 64            // partition blocks for hist/scatter
#define EPB ((NE + NBLKS - 1) / NBLKS)   // 25000 edges per partition block
#define STOT (NB * NBLKS)   // 50048 scan entries
#define SCAN_E 2048
#define NSB ((STOT + SCAN_E - 1) / SCAN_E)  // 25 scan blocks
#define GEMM0_BLOCKS 782    // ceil((NN/16)/8) for fused 512-thr gemm0

typedef __attribute__((ext_vector_type(8))) short short8;
typedef __attribute__((ext_vector_type(4))) float f32x4;
typedef unsigned int uint;
typedef unsigned short ushort;

__device__ inline ushort f2bf(float f) {
    uint u = __float_as_uint(f);
    u += 0x7FFFu + ((u >> 16) & 1u);
    return (ushort)(u >> 16);
}
__device__ inline float bf_lo(uint w) { return __uint_as_float(w << 16); }
__device__ inline float bf_hi(uint w) { return __uint_as_float(w & 0xFFFF0000u); }

// ---------------- fused MFMA GEMM body ----------------
// wid = global wave index (16 output rows per wave). wp = packed weights
// (LDS or global) — caller stages + syncs before calling.
template<int NCS, int NCN, bool XF32, bool ABF>
__device__ void gemm_body(int wid, int tid,
    const void* __restrict__ Hv, const short8* __restrict__ wp,
    const float* __restrict__ bias, void* __restrict__ Av, ushort* __restrict__ Bt)
{
    constexpr int NCT = (NCS + NCN) / 16;
    if (wid >= NN / 16) return;
    const int lane = tid & 63;
    const int m = lane & 15;
    const int q = lane >> 4;

    short8 af[4];
    if (XF32) {
        const float* hp = (const float*)Hv + (size_t)(wid * 16 + m) * 128;
        #pragma unroll
        for (int kt = 0; kt < 4; ++kt) {
            const float4 f0 = *(const float4*)(hp + kt * 32 + q * 8);
            const float4 f1 = *(const float4*)(hp + kt * 32 + q * 8 + 4);
            short8 v;
            v[0] = (short)f2bf(f0.x); v[1] = (short)f2bf(f0.y);
            v[2] = (short)f2bf(f0.z); v[3] = (short)f2bf(f0.w);
            v[4] = (short)f2bf(f1.x); v[5] = (short)f2bf(f1.y);
            v[6] = (short)f2bf(f1.z); v[7] = (short)f2bf(f1.w);
            af[kt] = v;
        }
    } else {
        const short8* hp = (const short8*)((const ushort*)Hv + (size_t)(wid * 16 + m) * 128);
        #pragma unroll
        for (int kt = 0; kt < 4; ++kt) af[kt] = hp[kt * 4 + q];
    }

    f32x4 acc[NCT];
    #pragma unroll
    for (int i = 0; i < NCT; ++i) acc[i] = (f32x4){0.f, 0.f, 0.f, 0.f};

    #pragma unroll
    for (int ct = 0; ct < NCT; ++ct) {
        #pragma unroll
        for (int kt = 0; kt < 4; ++kt) {
            const short8 bf = wp[(ct * 4 + kt) * 64 + lane];
            acc[ct] = __builtin_amdgcn_mfma_f32_16x16x32_bf16(af[kt], bf, acc[ct], 0, 0, 0);
        }
    }

    const int r0 = wid * 16 + q * 4;
    #pragma unroll
    for (int ct = 0; ct < NCS / 16; ++ct) {
        const int c = ct * 16 + m;
        const float bv = bias[c];
        #pragma unroll
        for (int r = 0; r < 4; ++r) {
            const float v = acc[ct][r] + bv;
            if (ABF) ((ushort*)Av)[(size_t)(r0 + r) * NCS + c] = f2bf(v);
            else     ((float*) Av)[(size_t)(r0 + r) * NCS + c] = v;
        }
    }
    #pragma unroll
    for (int ct = NCS / 16; ct < NCT; ++ct) {
        const int c = ct * 16 + m - NCS;
        #pragma unroll
        for (int r = 0; r < 4; ++r)
            Bt[(size_t)(r0 + r) * NCN + c] = f2bf(acc[ct][r]);
    }
}

template<int NCS, int NCN, bool XF32, bool ABF>
__global__ __launch_bounds__(512) void gemm_mfma_k(
    const void* __restrict__ Hv, const ushort* __restrict__ Wf,
    const float* __restrict__ bias, void* __restrict__ Av, ushort* __restrict__ Bt)
{
    constexpr int NCT = (NCS + NCN) / 16;
    __shared__ short8 wl[NCT * 4 * 64];
    uint4* dl = (uint4*)wl;
    const uint4* sg = (const uint4*)Wf;
    for (int i = threadIdx.x; i < NCT * 4 * 64; i += 512) dl[i] = sg[i];
    __syncthreads();
    gemm_body<NCS, NCN, XF32, ABF>(
        (blockIdx.x * 512 + threadIdx.x) >> 6, threadIdx.x, Hv, wl, bias, Av, Bt);
}

// ---------------- phase 1 + weight pack, one launch ----------------
__global__ __launch_bounds__(256) void phist_pack_k(
    const int* __restrict__ dst, int* __restrict__ histG,
    const float* __restrict__ ws0, const float* __restrict__ wn0, ushort* __restrict__ wf0,
    const float* __restrict__ ws1, const float* __restrict__ wn1, ushort* __restrict__ wf1,
    const float* __restrict__ ws2, const float* __restrict__ wn2, ushort* __restrict__ wf2)
{
    __shared__ int h[NB];
    const int t = threadIdx.x;
    if (blockIdx.x < NBLKS) {
        for (int i = t; i < NB; i += 256) h[i] = 0;
        __syncthreads();
        const int blk = blockIdx.x;
        const int e0 = blk * EPB;
        const int e1 = min(e0 + EPB, NE);
        for (int e = e0 + t; e < e1; e += 256)
            atomicAdd(&h[dst[e] >> BSH], 1);
        __syncthreads();
        for (int i = t; i < NB; i += 256)
            histG[i * NBLKS + blk] = h[i];
        return;
    }
    // weight pack: frag f = ct*4+kt; lane l holds B[k=kt*32+(l>>4)*8+j][n=ct*16+(l&15)]
    const int b = blockIdx.x - NBLKS;
    const float *ws, *wn; ushort* wf; int ncs, idx;
    if (b < 16)      { ws = ws0; wn = wn0; wf = wf0; ncs = 128; idx = b * 256 + t; }
    else if (b < 32) { ws = ws1; wn = wn1; wf = wf1; ncs = 128; idx = (b - 16) * 256 + t; }
    else             { ws = ws2; wn = wn2; wf = wf2; ncs = 64;  idx = (b - 32) * 256 + t; }
    const int total = (2 * ncs / 16) * 4 * 64;
    if (idx >= total) return;
    const int l = idx & 63;
    const int f = idx >> 6;
    const int kt = f & 3;
    const int ct = f >> 2;
    const int n = ct * 16 + (l & 15);
    const int k0 = kt * 32 + (l >> 4) * 8;
    uint w[4];
    #pragma unroll
    for (int p = 0; p < 4; ++p) {
        const int k = k0 + p * 2;
        float v0, v1;
        if (n < ncs) { v0 = ws[k * ncs + n];         v1 = ws[(k + 1) * ncs + n]; }
        else         { v0 = wn[k * ncs + (n - ncs)]; v1 = wn[(k + 1) * ncs + (n - ncs)]; }
        w[p] = (uint)f2bf(v0) | ((uint)f2bf(v1) << 16);
    }
    uint4 o; o.x = w[0]; o.y = w[1]; o.z = w[2]; o.w = w[3];
    ((uint4*)wf)[idx] = o;
}

// ---------------- scan of histG[STOT] ----------------
__global__ __launch_bounds__(256) void scan1_k(int* __restrict__ data, int* __restrict__ blksum) {
    __shared__ int lds[256];
    const int t = threadIdx.x;
    const int base = blockIdx.x * SCAN_E + t * 8;
    int v[8];
    int s = 0;
    #pragma unroll
    for (int i = 0; i < 8; ++i) {
        const int idx = base + i;
        v[i] = (idx < STOT) ? data[idx] : 0;
        s += v[i];
    }
    lds[t] = s;
    __syncthreads();
    #pragma unroll
    for (int off = 1; off < 256; off <<= 1) {
        const int cur = lds[t];
        const int y = (t >= off) ? lds[t - off] : 0;
        __syncthreads();
        lds[t] = cur + y;
        __syncthreads();
    }
    const int incl = lds[t];
    if (t == 255) blksum[blockIdx.x] = incl;
    int run = incl - s;
    #pragma unroll
    for (int i = 0; i < 8; ++i) {
        const int idx = base + i;
        if (idx < STOT) data[idx] = run;
        run += v[i];
    }
}

// scan3: every block scans the NSB block sums in LDS, adds its exclusive prefix
__global__ __launch_bounds__(256) void scan3_k(int* __restrict__ data, const int* __restrict__ blksum) {
    __shared__ int lds[256];
    const int t = threadIdx.x;
    lds[t] = (t < NSB) ? blksum[t] : 0;
    __syncthreads();
    #pragma unroll
    for (int off = 1; off < 256; off <<= 1) {
        const int cur = lds[t];
        const int y = (t >= off) ? lds[t - off] : 0;
        __syncthreads();
        lds[t] = cur + y;
        __syncthreads();
    }
    const int add = (blockIdx.x == 0) ? 0 : lds[blockIdx.x - 1];
    const int base = blockIdx.x * SCAN_E + t * 8;
    #pragma unroll
    for (int i = 0; i < 8; ++i) {
        const int idx = base + i;
        if (idx < STOT) data[idx] += add;
    }
}

// Phase 3 (+ fused layer-0 GEMM): scatter packed pairs using scanned bases.
// blocks [0,NBLKS): pscatter (wc aliases shared buf);
// blocks [NBLKS, NBLKS+GEMM0_BLOCKS): gemm0 with LDS-staged weights.
__global__ __launch_bounds__(512) void pscatter_gemm0_k(
    const int* __restrict__ src, const int* __restrict__ dst,
    const int* __restrict__ histG, int* __restrict__ pb,
    const float* __restrict__ x, const ushort* __restrict__ wf0,
    const float* __restrict__ b0, ushort* __restrict__ Abf, ushort* __restrict__ Bt)
{
    __shared__ uint4 sh[4096];   // 64 KB, shared by both roles
    const int t = threadIdx.x;
    if (blockIdx.x < NBLKS) {
        int* wc = (int*)sh;
        const int blk = blockIdx.x;
        for (int i = t; i < NB; i += 512) wc[i] = histG[i * NBLKS + blk];
        __syncthreads();
        const int e0 = blk * EPB;
        const int e1 = min(e0 + EPB, NE);
        for (int e = e0 + t; e < e1; e += 512) {
            const int d = dst[e];
            const int pos = atomicAdd(&wc[d >> BSH], 1);
            pb[pos] = (src[e] << BSH) | (d & (BND - 1));
        }
        return;
    }
    // stage 64 KB packed weights (8 waves share)
    const uint4* sg = (const uint4*)wf0;
    for (int i = t; i < 4096; i += 512) sh[i] = sg[i];
    __syncthreads();
    gemm_body<128, 128, true, true>(
        ((blockIdx.x - NBLKS) * 512 + t) >> 6, t, x, (const short8*)sh, b0, Abf, Bt);
}

// Phase 4: one block per bucket — local count, scan, place esrc, emit row[]
__global__ __launch_bounds__(256) void bucket_place_k(const int* __restrict__ histG,
                                                      const int* __restrict__ pb,
                                                      int* __restrict__ row,
                                                      int* __restrict__ esrc) {
    __shared__ int cnt[BND], wc[BND], excl[BND], scan[BND];
    const int b = blockIdx.x;
    const int t = threadIdx.x;
    if (t < BND) { cnt[t] = 0; wc[t] = 0; }
    __syncthreads();
    const int s0 = histG[b * NBLKS];
    const int s1 = (b + 1 < NB) ? histG[(b + 1) * NBLKS] : NE;
    for (int e = s0 + t; e < s1; e += 256)
        atomicAdd(&cnt[pb[e] & (BND - 1)], 1);
    __syncthreads();
    if (t < BND) scan[t] = cnt[t];
    __syncthreads();
    for (int off = 1; off < BND; off <<= 1) {
        int nv = 0;
        if (t < BND) {
            nv = scan[t];
            if (t >= off) nv += scan[t - off];
        }
        __syncthreads();
        if (t < BND) scan[t] = nv;
        __syncthreads();
    }
    if (t < BND) {
        const int ex = scan[t] - cnt[t];
        excl[t] = ex;
        const int node = b * BND + t;
        if (node <= NN) row[node] = s0 + ex;   // node==NN lands on row[NN]=NE
    }
    __syncthreads();
    for (int e = s0 + t; e < s1; e += 256) {
        const int p = pb[e];
        const int dl = p & (BND - 1);
        const int pos = s0 + excl[dl] + atomicAdd(&wc[dl], 1);
        esrc[pos] = p >> BSH;
    }
}

// ---------------- aggregation (R8 form — best measured) ----------------
// 128-wide: 2 nodes per wave (half-wave each, contiguous edges), uint2 loads.
__global__ __launch_bounds__(256) void agg128_k(
    const int* __restrict__ row, const int* __restrict__ esrc,
    const ushort* __restrict__ Bt, const ushort* __restrict__ Abf, ushort* __restrict__ Hb)
{
    const int w = (blockIdx.x * 256 + threadIdx.x) >> 6;
    const int half = (threadIdx.x >> 5) & 1;
    const int ln = threadIdx.x & 31;
    const int node = w * 2 + half;
    if (node >= NN) return;
    const int e0 = row[node];
    const int e1 = row[node + 1];
    const uint2* B = (const uint2*)Bt;          // row = 32 x uint2 (256B)
    float a0 = 0.f, a1 = 0.f, a2 = 0.f, a3 = 0.f;
    int e = e0;
    for (; e + 8 <= e1; e += 8) {
        int s[8];
        #pragma unroll
        for (int j = 0; j < 8; ++j) s[j] = esrc[e + j];
        uint2 v[8];
        #pragma unroll
        for (int j = 0; j < 8; ++j) v[j] = B[(size_t)s[j] * 32 + ln];
        #pragma unroll
        for (int j = 0; j < 8; ++j) {
            a0 += bf_lo(v[j].x); a1 += bf_hi(v[j].x);
            a2 += bf_lo(v[j].y); a3 += bf_hi(v[j].y);
        }
    }
    for (; e + 2 <= e1; e += 2) {
        const int s0 = esrc[e], s1 = esrc[e + 1];
        const uint2 v0 = B[(size_t)s0 * 32 + ln];
        const uint2 v1 = B[(size_t)s1 * 32 + ln];
        a0 += bf_lo(v0.x) + bf_lo(v1.x); a1 += bf_hi(v0.x) + bf_hi(v1.x);
        a2 += bf_lo(v0.y) + bf_lo(v1.y); a3 += bf_hi(v0.y) + bf_hi(v1.y);
    }
    if (e < e1) {
        const uint2 v = B[(size_t)esrc[e] * 32 + ln];
        a0 += bf_lo(v.x); a1 += bf_hi(v.x);
        a2 += bf_lo(v.y); a3 += bf_hi(v.y);
    }
    const int deg = e1 - e0;
    const float invd = (deg > 0) ? 1.0f / (float)deg : 0.0f;
    const uint2 aw = ((const uint2*)Abf)[(size_t)node * 32 + ln];
    const float v0 = fmaxf(bf_lo(aw.x) + a0 * invd, 0.f);
    const float v1 = fmaxf(bf_hi(aw.x) + a1 * invd, 0.f);
    const float v2 = fmaxf(bf_lo(aw.y) + a2 * invd, 0.f);
    const float v3 = fmaxf(bf_hi(aw.y) + a3 * invd, 0.f);
    uint2 o;
    o.x = (uint)f2bf(v0) | ((uint)f2bf(v1) << 16);
    o.y = (uint)f2bf(v2) | ((uint)f2bf(v3) << 16);
    ((uint2*)Hb)[(size_t)node * 32 + ln] = o;
}

// 64-wide: 4 nodes per wave (quarter-wave each), uint2 loads.
// out[node] += mean(Bt64[src]) fp32 in place, no relu.
__global__ __launch_bounds__(256) void agg64_k(
    const int* __restrict__ row, const int* __restrict__ esrc,
    const ushort* __restrict__ Bt, float* __restrict__ out)
{
    const int node = (blockIdx.x * 256 + threadIdx.x) >> 4;  // 16 lanes/node
    const int ln = threadIdx.x & 15;
    if (node >= NN) return;
    const int e0 = row[node];
    const int e1 = row[node + 1];
    const uint2* B = (const uint2*)Bt;          // row = 16 x uint2 (128B)
    float a0 = 0.f, a1 = 0.f, a2 = 0.f, a3 = 0.f;
    int e = e0;
    for (; e + 8 <= e1; e += 8) {
        int s[8];
        #pragma unroll
        for (int j = 0; j < 8; ++j) s[j] = esrc[e + j];
        uint2 v[8];
        #pragma unroll
        for (int j = 0; j < 8; ++j) v[j] = B[(size_t)s[j] * 16 + ln];
        #pragma unroll
        for (int j = 0; j < 8; ++j) {
            a0 += bf_lo(v[j].x); a1 += bf_hi(v[j].x);
            a2 += bf_lo(v[j].y); a3 += bf_hi(v[j].y);
        }
    }
    for (; e + 2 <= e1; e += 2) {
        const int s0 = esrc[e], s1 = esrc[e + 1];
        const uint2 v0 = B[(size_t)s0 * 16 + ln];
        const uint2 v1 = B[(size_t)s1 * 16 + ln];
        a0 += bf_lo(v0.x) + bf_lo(v1.x); a1 += bf_hi(v0.x) + bf_hi(v1.x);
        a2 += bf_lo(v0.y) + bf_lo(v1.y); a3 += bf_hi(v0.y) + bf_hi(v1.y);
    }
    if (e < e1) {
        const uint2 v = B[(size_t)esrc[e] * 16 + ln];
        a0 += bf_lo(v.x); a1 += bf_hi(v.x);
        a2 += bf_lo(v.y); a3 += bf_hi(v.y);
    }
    const int deg = e1 - e0;
    const float invd = (deg > 0) ? 1.0f / (float)deg : 0.0f;
    float4* op = (float4*)(out + (size_t)node * 64 + ln * 4);
    float4 o = *op;
    o.x += a0 * invd; o.y += a1 * invd;
    o.z += a2 * invd; o.w += a3 * invd;
    *op = o;
}

// ---------------- fp32 fallback path (small workspace) ----------------
__device__ inline float4 relu4f(float4 v) {
    v.x = fmaxf(v.x, 0.f); v.y = fmaxf(v.y, 0.f);
    v.z = fmaxf(v.z, 0.f); v.w = fmaxf(v.w, 0.f);
    return v;
}
template<int NCOL, bool RELU_IN, bool BIAS>
__global__ __launch_bounds__(256) void gemm_k(
    const float* in, const float* __restrict__ W,
    const float* __restrict__ bias, float* out)
{
    constexpr int K = 128;
    constexpr int QUADS = NCOL / 4;
    constexpr int G = 256 / QUADS;
    constexpr int RPT = 32 / G;
    __shared__ float Wlds[K * NCOL];
    {
        const float4* Wg = reinterpret_cast<const float4*>(W);
        float4* Wl = reinterpret_cast<float4*>(Wlds);
        #pragma unroll
        for (int i = 0; i < K * NCOL / 4 / 256; ++i)
            Wl[threadIdx.x + i * 256] = Wg[threadIdx.x + i * 256];
    }
    __syncthreads();
    const int tx = threadIdx.x % QUADS;
    const int ty = threadIdx.x / QUADS;
    const int row0 = blockIdx.x * 32;
    const float* rp[RPT];
    #pragma unroll
    for (int i = 0; i < RPT; ++i) rp[i] = in + (size_t)(row0 + ty + i * G) * K;
    float acc[RPT][4];
    #pragma unroll
    for (int i = 0; i < RPT; ++i) acc[i][0] = acc[i][1] = acc[i][2] = acc[i][3] = 0.f;
    #pragma unroll 2
    for (int kc = 0; kc < K; kc += 4) {
        float4 h4[RPT];
        #pragma unroll
        for (int i = 0; i < RPT; ++i) {
            h4[i] = *reinterpret_cast<const float4*>(rp[i] + kc);
            if (RELU_IN) h4[i] = relu4f(h4[i]);
        }
        #pragma unroll
        for (int kk = 0; kk < 4; ++kk) {
            const float4 w4 = *reinterpret_cast<const float4*>(&Wlds[(kc + kk) * NCOL + tx * 4]);
            #pragma unroll
            for (int i = 0; i < RPT; ++i) {
                const float hv = (&h4[i].x)[kk];
                acc[i][0] = fmaf(hv, w4.x, acc[i][0]);
                acc[i][1] = fmaf(hv, w4.y, acc[i][1]);
                acc[i][2] = fmaf(hv, w4.z, acc[i][2]);
                acc[i][3] = fmaf(hv, w4.w, acc[i][3]);
            }
        }
    }
    float4 b4 = make_float4(0.f, 0.f, 0.f, 0.f);
    if (BIAS) b4 = *reinterpret_cast<const float4*>(&bias[tx * 4]);
    #pragma unroll
    for (int i = 0; i < RPT; ++i) {
        const int r = row0 + ty + i * G;
        float4 o;
        o.x = acc[i][0] + b4.x; o.y = acc[i][1] + b4.y;
        o.z = acc[i][2] + b4.z; o.w = acc[i][3] + b4.w;
        *reinterpret_cast<float4*>(&out[(size_t)r * NCOL + tx * 4]) = o;
    }
}
__global__ void deg_k(const int* __restrict__ dst, float* __restrict__ deg, int E) {
    const int i = blockIdx.x * blockDim.x + threadIdx.x;
    if (i < E) atomicAdd(&deg[dst[i]], 1.0f);
}
__global__ void inv_k(float* deg, int n) {
    const int i = blockIdx.x * blockDim.x + threadIdx.x;
    if (i < n) deg[i] = 1.0f / fmaxf(deg[i], 1.0f);
}
__global__ __launch_bounds__(256) void scatter128_k(
    const int* __restrict__ src, const int* __restrict__ dst,
    const float* __restrict__ inv, const float* __restrict__ B, float* A, int E) {
    const int lane = threadIdx.x & 63;
    int w = (blockIdx.x * 256 + threadIdx.x) >> 6;
    const int nw = (gridDim.x * 256) >> 6;
    for (int e = w; e < E; e += nw) {
        const int s = src[e], d = dst[e];
        const float sc = inv[d];
        const float2 v = *reinterpret_cast<const float2*>(&B[(size_t)s * 128 + lane * 2]);
        atomicAdd(&A[(size_t)d * 128 + lane * 2    ], v.x * sc);
        atomicAdd(&A[(size_t)d * 128 + lane * 2 + 1], v.y * sc);
    }
}
__global__ __launch_bounds__(256) void scatter64_k(
    const int* __restrict__ src, const int* __restrict__ dst,
    const float* __restrict__ inv, const float* __restrict__ B, float* A, int E) {
    const int lane = threadIdx.x & 63;
    int w = (blockIdx.x * 256 + threadIdx.x) >> 6;
    const int nw = (gridDim.x * 256) >> 6;
    for (int e = w; e < E; e += nw) {
        const int s = src[e], d = dst[e];
        atomicAdd(&A[(size_t)d * 64 + lane], B[(size_t)s * 64 + lane] * inv[d]);
    }
}

extern "C" void kernel_launch(void* const* d_in, const int* in_sizes, int n_in,
                              void* d_out, int out_size, void* d_ws, size_t ws_size,
                              hipStream_t stream) {
    const float* x   = (const float*)d_in[0];
    const int*   src = (const int*)  d_in[1];
    const int*   dst = (const int*)  d_in[2];
    const float* ws0 = (const float*)d_in[3];
    const float* wn0 = (const float*)d_in[4];
    const float* b0  = (const float*)d_in[5];
    const float* ws1 = (const float*)d_in[6];
    const float* wn1 = (const float*)d_in[7];
    const float* b1  = (const float*)d_in[8];
    const float* ws2 = (const float*)d_in[9];
    const float* wn2 = (const float*)d_in[10];
    const float* b2  = (const float*)d_in[11];
    float* out = (float*)d_out;

    // workspace layout (byte offsets). histG (200KB) is ALIASED into the Hb
    // region: histG is fully consumed by bucket_place_k, which completes
    // (stream-ordered) before agg128_k first writes Hb.
    const size_t O_BLK  = 4096;       // scan blocksums
    const size_t O_ROW  = 16384;      // (NN+1)*4
    const size_t O_WF0  = 417792;     // 65536
    const size_t O_WF1  = 483328;     // 65536
    const size_t O_WF2  = 548864;     // 32768
    const size_t O_ESRC = 581632;     // 6400000
    const size_t O_PB   = 6983680;    // 6400000
    const size_t O_A    = 14286848;   // 25600000 (bf16)
    const size_t O_BT   = 39890944;   // 25600000
    const size_t O_HB   = 65495040;   // 25600000 (also hosts histG during CSR build)
    const size_t NEED   = 91095040;

    if (ws_size >= NEED) {
        int*    blks  = (int*)   ((char*)d_ws + O_BLK);
        int*    row   = (int*)   ((char*)d_ws + O_ROW);
        ushort* wf0   = (ushort*)((char*)d_ws + O_WF0);
        ushort* wf1   = (ushort*)((char*)d_ws + O_WF1);
        ushort* wf2   = (ushort*)((char*)d_ws + O_WF2);
        int*    esrc  = (int*)   ((char*)d_ws + O_ESRC);
        int*    pb    = (int*)   ((char*)d_ws + O_PB);
        ushort* Abf   = (ushort*)((char*)d_ws + O_A);
        ushort* Bt    = (ushort*)((char*)d_ws + O_BT);
        ushort* Hb    = (ushort*)((char*)d_ws + O_HB);
        int*    histG = (int*)   ((char*)d_ws + O_HB);   // dead before Hb is live

        // CSR build (+ weight pack fused, + gemm0 fused into pscatter)
        phist_pack_k<<<NBLKS + 40, 256, 0, stream>>>(dst, histG,
            ws0, wn0, wf0, ws1, wn1, wf1, ws2, wn2, wf2);
        scan1_k<<<NSB, 256, 0, stream>>>(histG, blks);
        scan3_k<<<NSB, 256, 0, stream>>>(histG, blks);
        pscatter_gemm0_k<<<NBLKS + GEMM0_BLOCKS, 512, 0, stream>>>(
            src, dst, histG, pb, x, wf0, b0, Abf, Bt);
        bucket_place_k<<<NB, 256, 0, stream>>>(histG, pb, row, esrc);

        const int AGG128_BLOCKS = (NN / 2 + 3) / 4;   // 12500 (2 nodes/wave)
        const int A64B = (NN + 15) / 16;              // 6250 (16 lanes/node)
        const int GEMM512_BLOCKS = (NN / 16 + 7) / 8; // 782 (8 waves/block)

        // layer 0 (gemm0 already done in fused launch)
        agg128_k<<<AGG128_BLOCKS, 256, 0, stream>>>(row, esrc, Bt, Abf, Hb);
        // layer 1
        gemm_mfma_k<128, 128, false, true ><<<GEMM512_BLOCKS, 512, 0, stream>>>(Hb, wf1, b1, Abf, Bt);
        agg128_k<<<AGG128_BLOCKS, 256, 0, stream>>>(row, esrc, Bt, Abf, Hb);
        // layer 2 (A fp32 straight to d_out; then in-place mean add)
        gemm_mfma_k<64, 64, false, false><<<GEMM512_BLOCKS, 512, 0, stream>>>(Hb, wf2, b2, out, Bt);
        agg64_k<<<A64B, 256, 0, stream>>>(row, esrc, Bt, out);
    } else {
        // fp32 atomic fallback
        float* inv = (float*)d_ws;
        float* H0  = (float*)((char*)d_ws + (1u << 20));
        float* Bf  = H0 + (size_t)NN * 128;
        const int GB = NN / 32;
        const int SC_BLOCKS = 4096;
        hipMemsetAsync(inv, 0, NN * sizeof(float), stream);
        deg_k<<<(NE + 255) / 256, 256, 0, stream>>>(dst, inv, NE);
        inv_k<<<(NN + 255) / 256, 256, 0, stream>>>(inv, NN);
        gemm_k<128, false, false><<<GB, 256, 0, stream>>>(x, wn0, nullptr, Bf);
        gemm_k<128, false, true ><<<GB, 256, 0, stream>>>(x, ws0, b0, H0);
        scatter128_k<<<SC_BLOCKS, 256, 0, stream>>>(src, dst, inv, Bf, H0, NE);
        gemm_k<128, true, false><<<GB, 256, 0, stream>>>(H0, wn1, nullptr, Bf);
        gemm_k<128, true, true ><<<GB, 256, 0, stream>>>(H0, ws1, b1, H0);
        scatter128_k<<<SC_BLOCKS, 256, 0, stream>>>(src, dst, inv, Bf, H0, NE);
        gemm_k<64, true, false><<<GB, 256, 0, stream>>>(H0, wn2, nullptr, Bf);
        gemm_k<64, true, true ><<<GB, 256, 0, stream>>>(H0, ws2, b2, out);
        scatter64_k<<<SC_BLOCKS, 256, 0, stream>>>(src, dst, inv, Bf, out, NE);
    }
}

// Round 7
// 353.243 us; speedup vs baseline: 1.1733x; 1.1733x over previous
//
#include <hip/hip_runtime.h>

// GraphSAGE 3-layer forward. R15:
//   NBLKS back to 256 (R14's 64 collapsed occupancy: parallelism >> traffic).
//   Overlap re-pairing: pscatter runs ALONE (small LDS, high occupancy);
//     gemm0 is now fused with bucket_place (512-thr launch) so the ~22us
//     bucket pass hides under the BW-bound gemm0 instead of the ~15us scatter.
//   bucket_place: pb entries held in registers across count/place passes
//     (statically-unrolled held[6], fallback to re-read if bucket > 3072).
//   phist/pscatter: int2 paired edge loads (EPB even, 8B-aligned).
//   agg128/agg64 frozen at R8 form (best measured 61.4us, VGPR 24).
// Per layer: [A | Bt] = H @ [Ws|Wn] (bf16 MFMA, fused self+neigh GEMM)
//            Hnext = relu(A + mean_{e:dst=d} Bt[src[e]]) stored bf16
//            (layer2: A fp32 straight to d_out, no relu)

#define NN 100000
#define NE 1600000
#define BSH 7               // 128 dst-nodes per bucket
#define BND 128
#define NB  782             // ceil(100000/128)
#define NBLKS 256           // partition blocks for hist/scatter
#define EPB ((NE + NBLKS - 1) / NBLKS)   // 6250 edges per partition block
#define STOT (NB * NBLKS)   // 200192 scan entries
#define SCAN_E 2048
#define NSB ((STOT + SCAN_E - 1) / SCAN_E)  // 98 scan blocks
#define GEMM0_BLOCKS 782    // ceil((NN/16)/8) for fused 512-thr gemm0
#define KMAX 6              // held pb entries per thread (6*512=3072 >= max bucket)

typedef __attribute__((ext_vector_type(8))) short short8;
typedef __attribute__((ext_vector_type(4))) float f32x4;
typedef unsigned int uint;
typedef unsigned short ushort;

__device__ inline ushort f2bf(float f) {
    uint u = __float_as_uint(f);
    u += 0x7FFFu + ((u >> 16) & 1u);
    return (ushort)(u >> 16);
}
__device__ inline float bf_lo(uint w) { return __uint_as_float(w << 16); }
__device__ inline float bf_hi(uint w) { return __uint_as_float(w & 0xFFFF0000u); }

// ---------------- fused MFMA GEMM body ----------------
// wid = global wave index (16 output rows per wave). wp = packed weights
// (LDS or global) — caller stages + syncs before calling.
template<int NCS, int NCN, bool XF32, bool ABF>
__device__ void gemm_body(int wid, int tid,
    const void* __restrict__ Hv, const short8* __restrict__ wp,
    const float* __restrict__ bias, void* __restrict__ Av, ushort* __restrict__ Bt)
{
    constexpr int NCT = (NCS + NCN) / 16;
    if (wid >= NN / 16) return;
    const int lane = tid & 63;
    const int m = lane & 15;
    const int q = lane >> 4;

    short8 af[4];
    if (XF32) {
        const float* hp = (const float*)Hv + (size_t)(wid * 16 + m) * 128;
        #pragma unroll
        for (int kt = 0; kt < 4; ++kt) {
            const float4 f0 = *(const float4*)(hp + kt * 32 + q * 8);
            const float4 f1 = *(const float4*)(hp + kt * 32 + q * 8 + 4);
            short8 v;
            v[0] = (short)f2bf(f0.x); v[1] = (short)f2bf(f0.y);
            v[2] = (short)f2bf(f0.z); v[3] = (short)f2bf(f0.w);
            v[4] = (short)f2bf(f1.x); v[5] = (short)f2bf(f1.y);
            v[6] = (short)f2bf(f1.z); v[7] = (short)f2bf(f1.w);
            af[kt] = v;
        }
    } else {
        const short8* hp = (const short8*)((const ushort*)Hv + (size_t)(wid * 16 + m) * 128);
        #pragma unroll
        for (int kt = 0; kt < 4; ++kt) af[kt] = hp[kt * 4 + q];
    }

    f32x4 acc[NCT];
    #pragma unroll
    for (int i = 0; i < NCT; ++i) acc[i] = (f32x4){0.f, 0.f, 0.f, 0.f};

    #pragma unroll
    for (int ct = 0; ct < NCT; ++ct) {
        #pragma unroll
        for (int kt = 0; kt < 4; ++kt) {
            const short8 bf = wp[(ct * 4 + kt) * 64 + lane];
            acc[ct] = __builtin_amdgcn_mfma_f32_16x16x32_bf16(af[kt], bf, acc[ct], 0, 0, 0);
        }
    }

    const int r0 = wid * 16 + q * 4;
    #pragma unroll
    for (int ct = 0; ct < NCS / 16; ++ct) {
        const int c = ct * 16 + m;
        const float bv = bias[c];
        #pragma unroll
        for (int r = 0; r < 4; ++r) {
            const float v = acc[ct][r] + bv;
            if (ABF) ((ushort*)Av)[(size_t)(r0 + r) * NCS + c] = f2bf(v);
            else     ((float*) Av)[(size_t)(r0 + r) * NCS + c] = v;
        }
    }
    #pragma unroll
    for (int ct = NCS / 16; ct < NCT; ++ct) {
        const int c = ct * 16 + m - NCS;
        #pragma unroll
        for (int r = 0; r < 4; ++r)
            Bt[(size_t)(r0 + r) * NCN + c] = f2bf(acc[ct][r]);
    }
}

template<int NCS, int NCN, bool XF32, bool ABF>
__global__ __launch_bounds__(512) void gemm_mfma_k(
    const void* __restrict__ Hv, const ushort* __restrict__ Wf,
    const float* __restrict__ bias, void* __restrict__ Av, ushort* __restrict__ Bt)
{
    constexpr int NCT = (NCS + NCN) / 16;
    __shared__ short8 wl[NCT * 4 * 64];
    uint4* dl = (uint4*)wl;
    const uint4* sg = (const uint4*)Wf;
    for (int i = threadIdx.x; i < NCT * 4 * 64; i += 512) dl[i] = sg[i];
    __syncthreads();
    gemm_body<NCS, NCN, XF32, ABF>(
        (blockIdx.x * 512 + threadIdx.x) >> 6, threadIdx.x, Hv, wl, bias, Av, Bt);
}

// ---------------- phase 1 + weight pack, one launch ----------------
__global__ __launch_bounds__(256) void phist_pack_k(
    const int* __restrict__ dst, int* __restrict__ histG,
    const float* __restrict__ ws0, const float* __restrict__ wn0, ushort* __restrict__ wf0,
    const float* __restrict__ ws1, const float* __restrict__ wn1, ushort* __restrict__ wf1,
    const float* __restrict__ ws2, const float* __restrict__ wn2, ushort* __restrict__ wf2)
{
    __shared__ int h[NB];
    const int t = threadIdx.x;
    if (blockIdx.x < NBLKS) {
        for (int i = t; i < NB; i += 256) h[i] = 0;
        __syncthreads();
        const int blk = blockIdx.x;
        const int e0 = blk * EPB;             // NE = NBLKS*EPB exactly; EPB even
        const int2* dp = (const int2*)(dst + e0);
        for (int k = t; k < EPB / 2; k += 256) {
            const int2 d2 = dp[k];
            atomicAdd(&h[d2.x >> BSH], 1);
            atomicAdd(&h[d2.y >> BSH], 1);
        }
        __syncthreads();
        for (int i = t; i < NB; i += 256)
            histG[i * NBLKS + blk] = h[i];
        return;
    }
    // weight pack: frag f = ct*4+kt; lane l holds B[k=kt*32+(l>>4)*8+j][n=ct*16+(l&15)]
    const int b = blockIdx.x - NBLKS;
    const float *ws, *wn; ushort* wf; int ncs, idx;
    if (b < 16)      { ws = ws0; wn = wn0; wf = wf0; ncs = 128; idx = b * 256 + t; }
    else if (b < 32) { ws = ws1; wn = wn1; wf = wf1; ncs = 128; idx = (b - 16) * 256 + t; }
    else             { ws = ws2; wn = wn2; wf = wf2; ncs = 64;  idx = (b - 32) * 256 + t; }
    const int total = (2 * ncs / 16) * 4 * 64;
    if (idx >= total) return;
    const int l = idx & 63;
    const int f = idx >> 6;
    const int kt = f & 3;
    const int ct = f >> 2;
    const int n = ct * 16 + (l & 15);
    const int k0 = kt * 32 + (l >> 4) * 8;
    uint w[4];
    #pragma unroll
    for (int p = 0; p < 4; ++p) {
        const int k = k0 + p * 2;
        float v0, v1;
        if (n < ncs) { v0 = ws[k * ncs + n];         v1 = ws[(k + 1) * ncs + n]; }
        else         { v0 = wn[k * ncs + (n - ncs)]; v1 = wn[(k + 1) * ncs + (n - ncs)]; }
        w[p] = (uint)f2bf(v0) | ((uint)f2bf(v1) << 16);
    }
    uint4 o; o.x = w[0]; o.y = w[1]; o.z = w[2]; o.w = w[3];
    ((uint4*)wf)[idx] = o;
}

// ---------------- scan of histG[STOT] ----------------
__global__ __launch_bounds__(256) void scan1_k(int* __restrict__ data, int* __restrict__ blksum) {
    __shared__ int lds[256];
    const int t = threadIdx.x;
    const int base = blockIdx.x * SCAN_E + t * 8;
    int v[8];
    int s = 0;
    #pragma unroll
    for (int i = 0; i < 8; ++i) {
        const int idx = base + i;
        v[i] = (idx < STOT) ? data[idx] : 0;
        s += v[i];
    }
    lds[t] = s;
    __syncthreads();
    #pragma unroll
    for (int off = 1; off < 256; off <<= 1) {
        const int cur = lds[t];
        const int y = (t >= off) ? lds[t - off] : 0;
        __syncthreads();
        lds[t] = cur + y;
        __syncthreads();
    }
    const int incl = lds[t];
    if (t == 255) blksum[blockIdx.x] = incl;
    int run = incl - s;
    #pragma unroll
    for (int i = 0; i < 8; ++i) {
        const int idx = base + i;
        if (idx < STOT) data[idx] = run;
        run += v[i];
    }
}

// scan3: every block scans the NSB block sums in LDS, adds its exclusive prefix
__global__ __launch_bounds__(256) void scan3_k(int* __restrict__ data, const int* __restrict__ blksum) {
    __shared__ int lds[256];
    const int t = threadIdx.x;
    lds[t] = (t < NSB) ? blksum[t] : 0;
    __syncthreads();
    #pragma unroll
    for (int off = 1; off < 256; off <<= 1) {
        const int cur = lds[t];
        const int y = (t >= off) ? lds[t - off] : 0;
        __syncthreads();
        lds[t] = cur + y;
        __syncthreads();
    }
    const int add = (blockIdx.x == 0) ? 0 : lds[blockIdx.x - 1];
    const int base = blockIdx.x * SCAN_E + t * 8;
    #pragma unroll
    for (int i = 0; i < 8; ++i) {
        const int idx = base + i;
        if (idx < STOT) data[idx] += add;
    }
}

// Phase 3: scatter packed pairs using scanned bases (standalone, small LDS).
__global__ __launch_bounds__(512) void pscatter_k(
    const int* __restrict__ src, const int* __restrict__ dst,
    const int* __restrict__ histG, int* __restrict__ pb)
{
    __shared__ int wc[NB];
    const int t = threadIdx.x;
    const int blk = blockIdx.x;
    for (int i = t; i < NB; i += 512) wc[i] = histG[i * NBLKS + blk];
    __syncthreads();
    const int e0 = blk * EPB;
    const int2* dp = (const int2*)(dst + e0);
    const int2* sp = (const int2*)(src + e0);
    for (int k = t; k < EPB / 2; k += 512) {
        const int2 d2 = dp[k];
        const int2 s2 = sp[k];
        const int p0 = atomicAdd(&wc[d2.x >> BSH], 1);
        pb[p0] = (s2.x << BSH) | (d2.x & (BND - 1));
        const int p1 = atomicAdd(&wc[d2.y >> BSH], 1);
        pb[p1] = (s2.y << BSH) | (d2.y & (BND - 1));
    }
}

// Phase 4 (+ fused layer-0 GEMM): blocks [0,NB): bucket_place with
// register-held pb entries; blocks [NB, NB+GEMM0_BLOCKS): gemm0 with
// LDS-staged weights.
__global__ __launch_bounds__(512) void bucketgemm0_k(
    const int* __restrict__ histG, const int* __restrict__ pb,
    int* __restrict__ row, int* __restrict__ esrc,
    const float* __restrict__ x, const ushort* __restrict__ wf0,
    const float* __restrict__ b0, ushort* __restrict__ Abf, ushort* __restrict__ Bt)
{
    __shared__ uint4 sh[4096];   // 64 KB, shared by both roles
    const int t = threadIdx.x;
    if (blockIdx.x < NB) {
        int* cnt  = (int*)sh;
        int* wc   = cnt + BND;
        int* excl = wc + BND;
        int* scn  = excl + BND;
        const int b = blockIdx.x;
        if (t < BND) { cnt[t] = 0; wc[t] = 0; }
        __syncthreads();
        const int s0 = histG[b * NBLKS];
        const int s1 = (b + 1 < NB) ? histG[(b + 1) * NBLKS] : NE;
        const int n = s1 - s0;
        int held[KMAX];
        const bool fits = (n <= KMAX * 512);
        if (fits) {
            #pragma unroll
            for (int i = 0; i < KMAX; ++i) {
                const int e = s0 + t + i * 512;
                held[i] = (e < s1) ? pb[e] : -1;
            }
            #pragma unroll
            for (int i = 0; i < KMAX; ++i)
                if (held[i] >= 0) atomicAdd(&cnt[held[i] & (BND - 1)], 1);
        } else {
            for (int e = s0 + t; e < s1; e += 512)
                atomicAdd(&cnt[pb[e] & (BND - 1)], 1);
        }
        __syncthreads();
        if (t < BND) scn[t] = cnt[t];
        __syncthreads();
        for (int off = 1; off < BND; off <<= 1) {
            int nv = 0;
            if (t < BND) {
                nv = scn[t];
                if (t >= off) nv += scn[t - off];
            }
            __syncthreads();
            if (t < BND) scn[t] = nv;
            __syncthreads();
        }
        if (t < BND) {
            const int ex = scn[t] - cnt[t];
            excl[t] = ex;
            const int node = b * BND + t;
            if (node <= NN) row[node] = s0 + ex;   // node==NN lands on row[NN]=NE
        }
        __syncthreads();
        if (fits) {
            #pragma unroll
            for (int i = 0; i < KMAX; ++i) {
                if (held[i] >= 0) {
                    const int p = held[i];
                    const int dl = p & (BND - 1);
                    const int pos = s0 + excl[dl] + atomicAdd(&wc[dl], 1);
                    esrc[pos] = p >> BSH;
                }
            }
        } else {
            for (int e = s0 + t; e < s1; e += 512) {
                const int p = pb[e];
                const int dl = p & (BND - 1);
                const int pos = s0 + excl[dl] + atomicAdd(&wc[dl], 1);
                esrc[pos] = p >> BSH;
            }
        }
        return;
    }
    // stage 64 KB packed weights (8 waves share)
    const uint4* sg = (const uint4*)wf0;
    for (int i = t; i < 4096; i += 512) sh[i] = sg[i];
    __syncthreads();
    gemm_body<128, 128, true, true>(
        ((blockIdx.x - NB) * 512 + t) >> 6, t, x, (const short8*)sh, b0, Abf, Bt);
}

// ---------------- aggregation (R8 form — best measured) ----------------
// 128-wide: 2 nodes per wave (half-wave each, contiguous edges), uint2 loads.
__global__ __launch_bounds__(256) void agg128_k(
    const int* __restrict__ row, const int* __restrict__ esrc,
    const ushort* __restrict__ Bt, const ushort* __restrict__ Abf, ushort* __restrict__ Hb)
{
    const int w = (blockIdx.x * 256 + threadIdx.x) >> 6;
    const int half = (threadIdx.x >> 5) & 1;
    const int ln = threadIdx.x & 31;
    const int node = w * 2 + half;
    if (node >= NN) return;
    const int e0 = row[node];
    const int e1 = row[node + 1];
    const uint2* B = (const uint2*)Bt;          // row = 32 x uint2 (256B)
    float a0 = 0.f, a1 = 0.f, a2 = 0.f, a3 = 0.f;
    int e = e0;
    for (; e + 8 <= e1; e += 8) {
        int s[8];
        #pragma unroll
        for (int j = 0; j < 8; ++j) s[j] = esrc[e + j];
        uint2 v[8];
        #pragma unroll
        for (int j = 0; j < 8; ++j) v[j] = B[(size_t)s[j] * 32 + ln];
        #pragma unroll
        for (int j = 0; j < 8; ++j) {
            a0 += bf_lo(v[j].x); a1 += bf_hi(v[j].x);
            a2 += bf_lo(v[j].y); a3 += bf_hi(v[j].y);
        }
    }
    for (; e + 2 <= e1; e += 2) {
        const int s0 = esrc[e], s1 = esrc[e + 1];
        const uint2 v0 = B[(size_t)s0 * 32 + ln];
        const uint2 v1 = B[(size_t)s1 * 32 + ln];
        a0 += bf_lo(v0.x) + bf_lo(v1.x); a1 += bf_hi(v0.x) + bf_hi(v1.x);
        a2 += bf_lo(v0.y) + bf_lo(v1.y); a3 += bf_hi(v0.y) + bf_hi(v1.y);
    }
    if (e < e1) {
        const uint2 v = B[(size_t)esrc[e] * 32 + ln];
        a0 += bf_lo(v.x); a1 += bf_hi(v.x);
        a2 += bf_lo(v.y); a3 += bf_hi(v.y);
    }
    const int deg = e1 - e0;
    const float invd = (deg > 0) ? 1.0f / (float)deg : 0.0f;
    const uint2 aw = ((const uint2*)Abf)[(size_t)node * 32 + ln];
    const float v0 = fmaxf(bf_lo(aw.x) + a0 * invd, 0.f);
    const float v1 = fmaxf(bf_hi(aw.x) + a1 * invd, 0.f);
    const float v2 = fmaxf(bf_lo(aw.y) + a2 * invd, 0.f);
    const float v3 = fmaxf(bf_hi(aw.y) + a3 * invd, 0.f);
    uint2 o;
    o.x = (uint)f2bf(v0) | ((uint)f2bf(v1) << 16);
    o.y = (uint)f2bf(v2) | ((uint)f2bf(v3) << 16);
    ((uint2*)Hb)[(size_t)node * 32 + ln] = o;
}

// 64-wide: 4 nodes per wave (quarter-wave each), uint2 loads.
// out[node] += mean(Bt64[src]) fp32 in place, no relu.
__global__ __launch_bounds__(256) void agg64_k(
    const int* __restrict__ row, const int* __restrict__ esrc,
    const ushort* __restrict__ Bt, float* __restrict__ out)
{
    const int node = (blockIdx.x * 256 + threadIdx.x) >> 4;  // 16 lanes/node
    const int ln = threadIdx.x & 15;
    if (node >= NN) return;
    const int e0 = row[node];
    const int e1 = row[node + 1];
    const uint2* B = (const uint2*)Bt;          // row = 16 x uint2 (128B)
    float a0 = 0.f, a1 = 0.f, a2 = 0.f, a3 = 0.f;
    int e = e0;
    for (; e + 8 <= e1; e += 8) {
        int s[8];
        #pragma unroll
        for (int j = 0; j < 8; ++j) s[j] = esrc[e + j];
        uint2 v[8];
        #pragma unroll
        for (int j = 0; j < 8; ++j) v[j] = B[(size_t)s[j] * 16 + ln];
        #pragma unroll
        for (int j = 0; j < 8; ++j) {
            a0 += bf_lo(v[j].x); a1 += bf_hi(v[j].x);
            a2 += bf_lo(v[j].y); a3 += bf_hi(v[j].y);
        }
    }
    for (; e + 2 <= e1; e += 2) {
        const int s0 = esrc[e], s1 = esrc[e + 1];
        const uint2 v0 = B[(size_t)s0 * 16 + ln];
        const uint2 v1 = B[(size_t)s1 * 16 + ln];
        a0 += bf_lo(v0.x) + bf_lo(v1.x); a1 += bf_hi(v0.x) + bf_hi(v1.x);
        a2 += bf_lo(v0.y) + bf_lo(v1.y); a3 += bf_hi(v0.y) + bf_hi(v1.y);
    }
    if (e < e1) {
        const uint2 v = B[(size_t)esrc[e] * 16 + ln];
        a0 += bf_lo(v.x); a1 += bf_hi(v.x);
        a2 += bf_lo(v.y); a3 += bf_hi(v.y);
    }
    const int deg = e1 - e0;
    const float invd = (deg > 0) ? 1.0f / (float)deg : 0.0f;
    float4* op = (float4*)(out + (size_t)node * 64 + ln * 4);
    float4 o = *op;
    o.x += a0 * invd; o.y += a1 * invd;
    o.z += a2 * invd; o.w += a3 * invd;
    *op = o;
}

// ---------------- fp32 fallback path (small workspace) ----------------
__device__ inline float4 relu4f(float4 v) {
    v.x = fmaxf(v.x, 0.f); v.y = fmaxf(v.y, 0.f);
    v.z = fmaxf(v.z, 0.f); v.w = fmaxf(v.w, 0.f);
    return v;
}
template<int NCOL, bool RELU_IN, bool BIAS>
__global__ __launch_bounds__(256) void gemm_k(
    const float* in, const float* __restrict__ W,
    const float* __restrict__ bias, float* out)
{
    constexpr int K = 128;
    constexpr int QUADS = NCOL / 4;
    constexpr int G = 256 / QUADS;
    constexpr int RPT = 32 / G;
    __shared__ float Wlds[K * NCOL];
    {
        const float4* Wg = reinterpret_cast<const float4*>(W);
        float4* Wl = reinterpret_cast<float4*>(Wlds);
        #pragma unroll
        for (int i = 0; i < K * NCOL / 4 / 256; ++i)
            Wl[threadIdx.x + i * 256] = Wg[threadIdx.x + i * 256];
    }
    __syncthreads();
    const int tx = threadIdx.x % QUADS;
    const int ty = threadIdx.x / QUADS;
    const int row0 = blockIdx.x * 32;
    const float* rp[RPT];
    #pragma unroll
    for (int i = 0; i < RPT; ++i) rp[i] = in + (size_t)(row0 + ty + i * G) * K;
    float acc[RPT][4];
    #pragma unroll
    for (int i = 0; i < RPT; ++i) acc[i][0] = acc[i][1] = acc[i][2] = acc[i][3] = 0.f;
    #pragma unroll 2
    for (int kc = 0; kc < K; kc += 4) {
        float4 h4[RPT];
        #pragma unroll
        for (int i = 0; i < RPT; ++i) {
            h4[i] = *reinterpret_cast<const float4*>(rp[i] + kc);
            if (RELU_IN) h4[i] = relu4f(h4[i]);
        }
        #pragma unroll
        for (int kk = 0; kk < 4; ++kk) {
            const float4 w4 = *reinterpret_cast<const float4*>(&Wlds[(kc + kk) * NCOL + tx * 4]);
            #pragma unroll
            for (int i = 0; i < RPT; ++i) {
                const float hv = (&h4[i].x)[kk];
                acc[i][0] = fmaf(hv, w4.x, acc[i][0]);
                acc[i][1] = fmaf(hv, w4.y, acc[i][1]);
                acc[i][2] = fmaf(hv, w4.z, acc[i][2]);
                acc[i][3] = fmaf(hv, w4.w, acc[i][3]);
            }
        }
    }
    float4 b4 = make_float4(0.f, 0.f, 0.f, 0.f);
    if (BIAS) b4 = *reinterpret_cast<const float4*>(&bias[tx * 4]);
    #pragma unroll
    for (int i = 0; i < RPT; ++i) {
        const int r = row0 + ty + i * G;
        float4 o;
        o.x = acc[i][0] + b4.x; o.y = acc[i][1] + b4.y;
        o.z = acc[i][2] + b4.z; o.w = acc[i][3] + b4.w;
        *reinterpret_cast<float4*>(&out[(size_t)r * NCOL + tx * 4]) = o;
    }
}
__global__ void deg_k(const int* __restrict__ dst, float* __restrict__ deg, int E) {
    const int i = blockIdx.x * blockDim.x + threadIdx.x;
    if (i < E) atomicAdd(&deg[dst[i]], 1.0f);
}
__global__ void inv_k(float* deg, int n) {
    const int i = blockIdx.x * blockDim.x + threadIdx.x;
    if (i < n) deg[i] = 1.0f / fmaxf(deg[i], 1.0f);
}
__global__ __launch_bounds__(256) void scatter128_k(
    const int* __restrict__ src, const int* __restrict__ dst,
    const float* __restrict__ inv, const float* __restrict__ B, float* A, int E) {
    const int lane = threadIdx.x & 63;
    int w = (blockIdx.x * 256 + threadIdx.x) >> 6;
    const int nw = (gridDim.x * 256) >> 6;
    for (int e = w; e < E; e += nw) {
        const int s = src[e], d = dst[e];
        const float sc = inv[d];
        const float2 v = *reinterpret_cast<const float2*>(&B[(size_t)s * 128 + lane * 2]);
        atomicAdd(&A[(size_t)d * 128 + lane * 2    ], v.x * sc);
        atomicAdd(&A[(size_t)d * 128 + lane * 2 + 1], v.y * sc);
    }
}
__global__ __launch_bounds__(256) void scatter64_k(
    const int* __restrict__ src, const int* __restrict__ dst,
    const float* __restrict__ inv, const float* __restrict__ B, float* A, int E) {
    const int lane = threadIdx.x & 63;
    int w = (blockIdx.x * 256 + threadIdx.x) >> 6;
    const int nw = (gridDim.x * 256) >> 6;
    for (int e = w; e < E; e += nw) {
        const int s = src[e], d = dst[e];
        atomicAdd(&A[(size_t)d * 64 + lane], B[(size_t)s * 64 + lane] * inv[d]);
    }
}

extern "C" void kernel_launch(void* const* d_in, const int* in_sizes, int n_in,
                              void* d_out, int out_size, void* d_ws, size_t ws_size,
                              hipStream_t stream) {
    const float* x   = (const float*)d_in[0];
    const int*   src = (const int*)  d_in[1];
    const int*   dst = (const int*)  d_in[2];
    const float* ws0 = (const float*)d_in[3];
    const float* wn0 = (const float*)d_in[4];
    const float* b0  = (const float*)d_in[5];
    const float* ws1 = (const float*)d_in[6];
    const float* wn1 = (const float*)d_in[7];
    const float* b1  = (const float*)d_in[8];
    const float* ws2 = (const float*)d_in[9];
    const float* wn2 = (const float*)d_in[10];
    const float* b2  = (const float*)d_in[11];
    float* out = (float*)d_out;

    // workspace layout (byte offsets). histG (0.8MB) is ALIASED into the Hb
    // region: histG is fully consumed by bucketgemm0_k, which completes
    // (stream-ordered) before agg128_k first writes Hb.
    const size_t O_BLK  = 4096;       // scan blocksums
    const size_t O_ROW  = 16384;      // (NN+1)*4
    const size_t O_WF0  = 417792;     // 65536
    const size_t O_WF1  = 483328;     // 65536
    const size_t O_WF2  = 548864;     // 32768
    const size_t O_ESRC = 581632;     // 6400000
    const size_t O_PB   = 6983680;    // 6400000
    const size_t O_A    = 14286848;   // 25600000 (bf16)
    const size_t O_BT   = 39890944;   // 25600000
    const size_t O_HB   = 65495040;   // 25600000 (also hosts histG during CSR build)
    const size_t NEED   = 91095040;

    if (ws_size >= NEED) {
        int*    blks  = (int*)   ((char*)d_ws + O_BLK);
        int*    row   = (int*)   ((char*)d_ws + O_ROW);
        ushort* wf0   = (ushort*)((char*)d_ws + O_WF0);
        ushort* wf1   = (ushort*)((char*)d_ws + O_WF1);
        ushort* wf2   = (ushort*)((char*)d_ws + O_WF2);
        int*    esrc  = (int*)   ((char*)d_ws + O_ESRC);
        int*    pb    = (int*)   ((char*)d_ws + O_PB);
        ushort* Abf   = (ushort*)((char*)d_ws + O_A);
        ushort* Bt    = (ushort*)((char*)d_ws + O_BT);
        ushort* Hb    = (ushort*)((char*)d_ws + O_HB);
        int*    histG = (int*)   ((char*)d_ws + O_HB);   // dead before Hb is live

        // CSR build (+ weight pack fused; gemm0 fused with bucket_place)
        phist_pack_k<<<NBLKS + 40, 256, 0, stream>>>(dst, histG,
            ws0, wn0, wf0, ws1, wn1, wf1, ws2, wn2, wf2);
        scan1_k<<<NSB, 256, 0, stream>>>(histG, blks);
        scan3_k<<<NSB, 256, 0, stream>>>(histG, blks);
        pscatter_k<<<NBLKS, 512, 0, stream>>>(src, dst, histG, pb);
        bucketgemm0_k<<<NB + GEMM0_BLOCKS, 512, 0, stream>>>(
            histG, pb, row, esrc, x, wf0, b0, Abf, Bt);

        const int AGG128_BLOCKS = (NN / 2 + 3) / 4;   // 12500 (2 nodes/wave)
        const int A64B = (NN + 15) / 16;              // 6250 (16 lanes/node)
        const int GEMM512_BLOCKS = (NN / 16 + 7) / 8; // 782 (8 waves/block)

        // layer 0 (gemm0 already done in fused launch)
        agg128_k<<<AGG128_BLOCKS, 256, 0, stream>>>(row, esrc, Bt, Abf, Hb);
        // layer 1
        gemm_mfma_k<128, 128, false, true ><<<GEMM512_BLOCKS, 512, 0, stream>>>(Hb, wf1, b1, Abf, Bt);
        agg128_k<<<AGG128_BLOCKS, 256, 0, stream>>>(row, esrc, Bt, Abf, Hb);
        // layer 2 (A fp32 straight to d_out; then in-place mean add)
        gemm_mfma_k<64, 64, false, false><<<GEMM512_BLOCKS, 512, 0, stream>>>(Hb, wf2, b2, out, Bt);
        agg64_k<<<A64B, 256, 0, stream>>>(row, esrc, Bt, out);
    } else {
        // fp32 atomic fallback
        float* inv = (float*)d_ws;
        float* H0  = (float*)((char*)d_ws + (1u << 20));
        float* Bf  = H0 + (size_t)NN * 128;
        const int GB = NN / 32;
        const int SC_BLOCKS = 4096;
        hipMemsetAsync(inv, 0, NN * sizeof(float), stream);
        deg_k<<<(NE + 255) / 256, 256, 0, stream>>>(dst, inv, NE);
        inv_k<<<(NN + 255) / 256, 256, 0, stream>>>(inv, NN);
        gemm_k<128, false, false><<<GB, 256, 0, stream>>>(x, wn0, nullptr, Bf);
        gemm_k<128, false, true ><<<GB, 256, 0, stream>>>(x, ws0, b0, H0);
        scatter128_k<<<SC_BLOCKS, 256, 0, stream>>>(src, dst, inv, Bf, H0, NE);
        gemm_k<128, true, false><<<GB, 256, 0, stream>>>(H0, wn1, nullptr, Bf);
        gemm_k<128, true, true ><<<GB, 256, 0, stream>>>(H0, ws1, b1, H0);
        scatter128_k<<<SC_BLOCKS, 256, 0, stream>>>(src, dst, inv, Bf, H0, NE);
        gemm_k<64, true, false><<<GB, 256, 0, stream>>>(H0, wn2, nullptr, Bf);
        gemm_k<64, true, true ><<<GB, 256, 0, stream>>>(H0, ws2, b2, out);
        scatter64_k<<<SC_BLOCKS, 256, 0, stream>>>(src, dst, inv, Bf, out, NE);
    }
}